// Round 3
// baseline (746.117 us; speedup 1.0000x reference)
//
#include <hip/hip_runtime.h>

#define NPIX 9216
#define NL   21
#define WW   96
#define JSD  16
#define L2E  1.44269504088896340736f

typedef __bf16 bf16x8 __attribute__((ext_vector_type(8)));
typedef float  f32x16 __attribute__((ext_vector_type(16)));

__device__ __forceinline__ float fexp2(float x) { return __builtin_amdgcn_exp2f(x); }

// ---------- prep: bilateral features + analytic spatial norm + QhT const rows ----------
__global__ __launch_bounds__(256) void featK(const float* __restrict__ img,
                                             float* __restrict__ Fi, float* __restrict__ Fj,
                                             float* __restrict__ norm_s, __bf16* __restrict__ QhT) {
    int i = blockIdx.x * 256 + threadIdx.x;
    if (i >= NPIX) return;
    int y = i / WW, x = i - y * WW;
    float f0 = (float)x * (1.0f / 160.0f);
    float f1 = (float)y * (1.0f / 160.0f);
    float f2 = img[0 * NPIX + i] * (1.0f / 3.0f);
    float f3 = img[1 * NPIX + i] * (1.0f / 3.0f);
    float f4 = img[2 * NPIX + i] * (1.0f / 3.0f);
    float st = 0.5f * (f0*f0 + f1*f1 + f2*f2 + f3*f3 + f4*f4) * L2E;
    float* a = Fi + (size_t)i * 8;
    float* b = Fj + (size_t)i * 8;
    a[0]=f0; a[1]=f1; a[2]=f2; a[3]=f3; a[4]=f4; a[5]=st; a[6]=0.f; a[7]=0.f;
    b[0]=f0*L2E; b[1]=f1*L2E; b[2]=f2*L2E; b[3]=f3*L2E; b[4]=f4*L2E; b[5]=st; b[6]=0.f; b[7]=0.f;
    // constant rows of bf16 Q^T: row 21 = 1.0 (denominator), rows 22..31 = 0
    QhT[(size_t)21 * NPIX + i] = (__bf16)1.0f;
    #pragma unroll
    for (int l = 22; l < 32; l++) QhT[(size_t)l * NPIX + i] = (__bf16)0.0f;
    // spatial (gamma=3) row-sum, exactly separable: sum_j Ks[i,j] = sx * sy
    const float cs = (-0.5f / 9.0f) * L2E;
    float sx = 0.f, sy = 0.f;
    for (int t = 0; t < WW; t++) {
        float dx = (float)(x - t); sx += fexp2(cs * dx * dx);
        float dy = (float)(y - t); sy += fexp2(cs * dy * dy);
    }
    norm_s[i] = 1.0f / (sx * sy + 1e-8f);
}

// ---------- fold 21x21 matrices: Ms = C @ Ws, Mb = C @ Wb ----------
__global__ __launch_bounds__(448) void matK(const float* __restrict__ Cm, const float* __restrict__ Wsm,
                                            const float* __restrict__ Wbm,
                                            float* __restrict__ Ms, float* __restrict__ Mb) {
    int t = threadIdx.x;
    if (t >= NL * NL) return;
    int l = t / NL, p = t - l * NL;
    float a = 0.f, b = 0.f;
    for (int m = 0; m < NL; m++) {
        float c = Cm[l * NL + m];
        a = fmaf(c, Wsm[m * NL + p], a);
        b = fmaf(c, Wbm[m * NL + p], b);
    }
    Ms[t] = a; Mb[t] = b;
}

// ---------- softmax over labels: f32 label-major (Qlm) + bf16 label-major (QhT) ----------
__global__ __launch_bounds__(256) void softmaxK(const float* __restrict__ cur,
                                                __bf16* __restrict__ QhT, float* __restrict__ Qlm) {
    int i = blockIdx.x * 256 + threadIdx.x;
    if (i >= NPIX) return;
    float v[NL]; float m = -1e30f;
    #pragma unroll
    for (int l = 0; l < NL; l++) { v[l] = cur[l * NPIX + i]; m = fmaxf(m, v[l]); }
    float s = 0.f;
    #pragma unroll
    for (int l = 0; l < NL; l++) { v[l] = fexp2((v[l] - m) * L2E); s += v[l]; }
    float inv = 1.0f / s;
    #pragma unroll
    for (int l = 0; l < NL; l++) {
        float q = v[l] * inv;
        Qlm[l * NPIX + i] = q;
        QhT[(size_t)l * NPIX + i] = (__bf16)q;
    }
}

// ---------- spatial filtering: exact separable Gaussian, x-pass then y-pass ----------
__global__ __launch_bounds__(256) void spatX(const float* __restrict__ Qlm, float* __restrict__ S1) {
    int tid = blockIdx.x * 256 + threadIdx.x;   // NL*NPIX exact
    int l = tid / NPIX, rem = tid - l * NPIX;
    int y = rem / WW, x1 = rem - y * WW;
    const float cs = (-0.5f / 9.0f) * L2E;
    const float* row = Qlm + l * NPIX + y * WW;
    float acc = 0.f;
    for (int x2 = 0; x2 < WW; x2++) {
        float d = (float)(x1 - x2);
        acc = fmaf(fexp2(cs * d * d), row[x2], acc);
    }
    S1[tid] = acc;
}

__global__ __launch_bounds__(256) void spatY(const float* __restrict__ S1, const float* __restrict__ norm_s,
                                             float* __restrict__ Sp) {
    int tid = blockIdx.x * 256 + threadIdx.x;
    int l = tid / NPIX, rem = tid - l * NPIX;
    int y1 = rem / WW, x = rem - y1 * WW;
    const float cs = (-0.5f / 9.0f) * L2E;
    float acc = 0.f;
    for (int y2 = 0; y2 < WW; y2++) {
        float d = (float)(y1 - y2);
        acc = fmaf(fexp2(cs * d * d), S1[l * NPIX + y2 * WW + x], acc);
    }
    Sp[tid] = acc * norm_s[rem];
}

// ---------- bilateral via MFMA: C[i(32), n(32)] += K_tile[i,16j] @ Qh[16j, n] ----------
// 4 waves/block, wave owns 32 i-pixels; blockIdx.y = j-chunk; no LDS, no barriers.
// A-frag (eval'd in regs): lane m=lane&31, k=(lane>>5)*8+e. B-frag: lane n=lane&31, same k.
// Any within-group k-permutation mismatch cancels (same formula on A and B; sum over j).
__global__ __launch_bounds__(256) void bilatM(const __bf16* __restrict__ QhT,
                                              const float* __restrict__ Fi,
                                              const float* __restrict__ Fj,
                                              float* __restrict__ part, int njc) {
    int tid = threadIdx.x;
    int w = tid >> 6, lane = tid & 63;
    int n = lane & 31, kb = lane >> 5;
    int jc = blockIdx.y;
    int ibase = blockIdx.x * 128 + w * 32;
    int i = ibase + n;

    const float4 fA = *reinterpret_cast<const float4*>(Fi + (size_t)i * 8);
    const float4 fB = *reinterpret_cast<const float4*>(Fi + (size_t)i * 8 + 4);

    f32x16 acc = {};
    const __bf16* qrow = QhT + (size_t)n * NPIX;
    int jbeg = jc * njc;
    for (int jb = jbeg; jb < jbeg + njc; jb += 16) {
        int j0 = jb + kb * 8;
        bf16x8 bq = *reinterpret_cast<const bf16x8*>(qrow + j0);
        bf16x8 ka;
        #pragma unroll
        for (int e = 0; e < 8; e++) {
            const float4 a = *reinterpret_cast<const float4*>(Fj + (size_t)(j0 + e) * 8);
            const float4 b = *reinterpret_cast<const float4*>(Fj + (size_t)(j0 + e) * 8 + 4);
            float bb = -(fB.y + b.y);
            bb = fmaf(a.x, fA.x, bb);
            bb = fmaf(a.y, fA.y, bb);
            bb = fmaf(a.z, fA.z, bb);
            bb = fmaf(a.w, fA.w, bb);
            bb = fmaf(b.x, fB.x, bb);
            ka[e] = (__bf16)fexp2(bb);
        }
        acc = __builtin_amdgcn_mfma_f32_32x32x16_bf16(ka, bq, acc, 0, 0, 0);
    }
    if (n < 22) {
        float* p = part + ((size_t)jc * 22 + n) * NPIX + ibase;
        #pragma unroll
        for (int q = 0; q < 16; q++) {
            int r = (q & 3) + 8 * (q >> 2) + 4 * kb;   // verified C/D row map (m74/m101)
            p[r] = acc[q];
        }
    }
}

// ---------- reduce j-chunks (22 rows incl. denominator); norm applied in combK ----------
__global__ __launch_bounds__(256) void bredK(const float* __restrict__ part, float* __restrict__ Bl, int js) {
    int t = blockIdx.x * 256 + threadIdx.x;   // 22*NPIX = 202752 exact (792 blocks)
    float a = 0.f;
    for (int jc = 0; jc < js; jc++) a += part[(size_t)jc * 22 * NPIX + t];
    Bl[t] = a;
}

// ---------- combine: cur = Ms@Sp + Mb@(diag(1/denom) Bl) + unary ----------
__global__ __launch_bounds__(256) void combK(const float* __restrict__ Sp, const float* __restrict__ Bl,
                                             const float* __restrict__ Ms, const float* __restrict__ Mb,
                                             const float* __restrict__ unary, float* __restrict__ outp) {
    __shared__ float sMs[NL * NL], sMb[NL * NL];
    int t = threadIdx.x;
    for (int k = t; k < NL * NL; k += 256) { sMs[k] = Ms[k]; sMb[k] = Mb[k]; }
    __syncthreads();
    int i = blockIdx.x * 256 + t;
    if (i >= NPIX) return;
    float inv = 1.0f / (Bl[(size_t)21 * NPIX + i] + 1e-8f);
    float sp[NL], bl[NL];
    #pragma unroll
    for (int p = 0; p < NL; p++) { sp[p] = Sp[p * NPIX + i]; bl[p] = Bl[p * NPIX + i] * inv; }
    for (int l = 0; l < NL; l++) {
        float a = unary[l * NPIX + i];
        #pragma unroll
        for (int p = 0; p < NL; p++) {
            a = fmaf(sMs[l * NL + p], sp[p], a);
            a = fmaf(sMb[l * NL + p], bl[p], a);
        }
        outp[l * NPIX + i] = a;
    }
}

extern "C" void kernel_launch(void* const* d_in, const int* in_sizes, int n_in,
                              void* d_out, int out_size, void* d_ws, size_t ws_size,
                              hipStream_t stream) {
    const float* img   = (const float*)d_in[0];
    const float* logit = (const float*)d_in[1];
    const float* Wsm   = (const float*)d_in[2];
    const float* Wbm   = (const float*)d_in[3];
    const float* Cm    = (const float*)d_in[4];
    float* out = (float*)d_out;
    float* ws  = (float*)d_ws;

    // workspace layout (float offsets)
    float* Fi     = ws;                       // 73728
    float* Fj     = Fi + NPIX * 8;            // 73728
    float* Qlm    = Fj + NPIX * 8;            // 193536
    float* S1     = Qlm + NL * NPIX;          // 193536
    float* Sp     = S1 + NL * NPIX;           // 193536
    float* Bl     = Sp + NL * NPIX;           // 202752 (22 rows)
    float* norm_s = Bl + 22 * NPIX;           // 9216
    float* Ms     = norm_s + NPIX;            // 448
    float* Mb     = Ms + 448;                 // 448
    __bf16* QhT   = (__bf16*)(Mb + 448);      // 32*NPIX bf16 = 147456 floats
    float* part   = ws + 1088384;             // js*22*NPIX

    int js = JSD;
    while (js > 1 && (1088384ull + (size_t)js * 22 * NPIX) * 4 > ws_size) js >>= 1;
    int njc = NPIX / js;

    featK<<<36, 256, 0, stream>>>(img, Fi, Fj, norm_s, QhT);
    matK<<<1, 448, 0, stream>>>(Cm, Wsm, Wbm, Ms, Mb);
    for (int it = 0; it < 5; ++it) {
        const float* cur = (it == 0) ? logit : out;
        softmaxK<<<36, 256, 0, stream>>>(cur, QhT, Qlm);
        spatX<<<756, 256, 0, stream>>>(Qlm, S1);
        spatY<<<756, 256, 0, stream>>>(S1, norm_s, Sp);
        bilatM<<<dim3(NPIX / 128, js), 256, 0, stream>>>(QhT, Fi, Fj, part, njc);
        bredK<<<792, 256, 0, stream>>>(part, Bl, js);
        combK<<<36, 256, 0, stream>>>(Sp, Bl, Ms, Mb, logit, out);
    }
}

// Round 4
// 696.144 us; speedup vs baseline: 1.0718x; 1.0718x over previous
//
#include <hip/hip_runtime.h>

#define NPIX 9216
#define NL   21
#define WW   96
#define RAD  16
#define L2E  1.44269504088896340736f

typedef __bf16 bf16x8 __attribute__((ext_vector_type(8)));
typedef float  f32x16 __attribute__((ext_vector_type(16)));

__device__ __forceinline__ float fexp2(float x) { return __builtin_amdgcn_exp2f(x); }

// ---------- prep: bilateral features + truncated spatial norm + QhT const rows ----------
__global__ __launch_bounds__(256) void featK(const float* __restrict__ img,
                                             float* __restrict__ Fi, float* __restrict__ Fj,
                                             float* __restrict__ norm_s, __bf16* __restrict__ QhT) {
    int i = blockIdx.x * 256 + threadIdx.x;
    if (i >= NPIX) return;
    int y = i / WW, x = i - y * WW;
    float f0 = (float)x * (1.0f / 160.0f);
    float f1 = (float)y * (1.0f / 160.0f);
    float f2 = img[0 * NPIX + i] * (1.0f / 3.0f);
    float f3 = img[1 * NPIX + i] * (1.0f / 3.0f);
    float f4 = img[2 * NPIX + i] * (1.0f / 3.0f);
    float st = 0.5f * (f0*f0 + f1*f1 + f2*f2 + f3*f3 + f4*f4) * L2E;
    float* a = Fi + (size_t)i * 8;
    float* b = Fj + (size_t)i * 8;
    a[0]=f0; a[1]=f1; a[2]=f2; a[3]=f3; a[4]=f4; a[5]=st; a[6]=0.f; a[7]=0.f;
    b[0]=f0*L2E; b[1]=f1*L2E; b[2]=f2*L2E; b[3]=f3*L2E; b[4]=f4*L2E; b[5]=st; b[6]=0.f; b[7]=0.f;
    QhT[(size_t)21 * NPIX + i] = (__bf16)1.0f;
    #pragma unroll
    for (int l = 22; l < 32; l++) QhT[(size_t)l * NPIX + i] = (__bf16)0.0f;
    // truncated spatial row-sum (consistent with truncated filter): sum = sx * sy
    const float cs = (-0.5f / 9.0f) * L2E;
    float sx = 0.f, sy = 0.f;
    int xa = max(0, x - RAD), xb = min(WW - 1, x + RAD);
    int ya = max(0, y - RAD), yb = min(WW - 1, y + RAD);
    for (int t = xa; t <= xb; t++) { float dx = (float)(x - t); sx += fexp2(cs * dx * dx); }
    for (int t = ya; t <= yb; t++) { float dy = (float)(y - t); sy += fexp2(cs * dy * dy); }
    norm_s[i] = 1.0f / (sx * sy + 1e-8f);
}

// ---------- fold 21x21 matrices: Ms = C @ Ws, Mb = C @ Wb ----------
__global__ __launch_bounds__(448) void matK(const float* __restrict__ Cm, const float* __restrict__ Wsm,
                                            const float* __restrict__ Wbm,
                                            float* __restrict__ Ms, float* __restrict__ Mb) {
    int t = threadIdx.x;
    if (t >= NL * NL) return;
    int l = t / NL, p = t - l * NL;
    float a = 0.f, b = 0.f;
    for (int m = 0; m < NL; m++) {
        float c = Cm[l * NL + m];
        a = fmaf(c, Wsm[m * NL + p], a);
        b = fmaf(c, Wbm[m * NL + p], b);
    }
    Ms[t] = a; Mb[t] = b;
}

// ---------- softmax over labels (iter 0 only) ----------
__global__ __launch_bounds__(256) void softmaxK(const float* __restrict__ cur,
                                                __bf16* __restrict__ QhT, float* __restrict__ Qlm) {
    int i = blockIdx.x * 256 + threadIdx.x;
    if (i >= NPIX) return;
    float v[NL]; float m = -1e30f;
    #pragma unroll
    for (int l = 0; l < NL; l++) { v[l] = cur[l * NPIX + i]; m = fmaxf(m, v[l]); }
    float s = 0.f;
    #pragma unroll
    for (int l = 0; l < NL; l++) { v[l] = fexp2((v[l] - m) * L2E); s += v[l]; }
    float inv = 1.0f / s;
    #pragma unroll
    for (int l = 0; l < NL; l++) {
        float q = v[l] * inv;
        Qlm[l * NPIX + i] = q;
        QhT[(size_t)l * NPIX + i] = (__bf16)q;
    }
}

// ---------- spatial filtering: truncated separable Gaussian (|d|<=16) ----------
__global__ __launch_bounds__(256) void spatX(const float* __restrict__ Qlm, float* __restrict__ S1) {
    int tid = blockIdx.x * 256 + threadIdx.x;   // NL*NPIX exact
    int l = tid / NPIX, rem = tid - l * NPIX;
    int y = rem / WW, x1 = rem - y * WW;
    const float cs = (-0.5f / 9.0f) * L2E;
    const float* row = Qlm + l * NPIX + y * WW;
    int a = max(0, x1 - RAD), b = min(WW - 1, x1 + RAD);
    float acc = 0.f;
    for (int x2 = a; x2 <= b; x2++) {
        float d = (float)(x1 - x2);
        acc = fmaf(fexp2(cs * d * d), row[x2], acc);
    }
    S1[tid] = acc;
}

__global__ __launch_bounds__(256) void spatY(const float* __restrict__ S1, const float* __restrict__ norm_s,
                                             float* __restrict__ Sp) {
    int tid = blockIdx.x * 256 + threadIdx.x;
    int l = tid / NPIX, rem = tid - l * NPIX;
    int y1 = rem / WW, x = rem - y1 * WW;
    const float cs = (-0.5f / 9.0f) * L2E;
    int a = max(0, y1 - RAD), b = min(WW - 1, y1 + RAD);
    float acc = 0.f;
    for (int y2 = a; y2 <= b; y2++) {
        float d = (float)(y1 - y2);
        acc = fmaf(fexp2(cs * d * d), S1[l * NPIX + y2 * WW + x], acc);
    }
    Sp[tid] = acc * norm_s[rem];
}

// ---------- bilateral via MFMA, register-hoisted loads + LDS-staged Q ----------
// 128 threads (2 waves); wave owns 32 i-pixels; blockIdx.y = j-chunk.
// Q tile [32 labels][32 j] staged to LDS double-buffered (1 barrier/stage).
__global__ __launch_bounds__(128, 3) void bilatM(const __bf16* __restrict__ QhT,
                                                 const float* __restrict__ Fi,
                                                 const float* __restrict__ Fj,
                                                 float* __restrict__ part, int njc) {
    __shared__ __bf16 sQ[2][32][40];   // 80B rows (16B-aligned), 5 KB total
    int tid = threadIdx.x;
    int w = tid >> 6, lane = tid & 63;
    int n = lane & 31, kb = lane >> 5;
    int jc = blockIdx.y;
    int ibase = blockIdx.x * 64 + w * 32;
    int i = ibase + n;

    const float4 fA = *reinterpret_cast<const float4*>(Fi + (size_t)i * 8);
    const float4 fB = *reinterpret_cast<const float4*>(Fi + (size_t)i * 8 + 4);

    // staging role: thread t loads row (t&31), 8-elem chunk (t>>5)
    int srow = tid & 31, scb = tid >> 5;
    const __bf16* qsrc = QhT + (size_t)srow * NPIX + scb * 8;

    f32x16 acc = {};
    int jbeg = jc * njc;
    int nst = njc / 32;
    float4 g = *reinterpret_cast<const float4*>(qsrc + jbeg);
    int cur = 0;

    for (int s = 0; s < nst; s++) {
        int jb = jbeg + s * 32;
        *reinterpret_cast<float4*>(&sQ[cur][srow][scb * 8]) = g;
        if (s + 1 < nst) g = *reinterpret_cast<const float4*>(qsrc + jb + 32);
        __syncthreads();
        #pragma unroll
        for (int ki = 0; ki < 2; ki++) {
            int j0 = jb + ki * 16 + kb * 8;
            float4 ra[8], rb[8];
            #pragma unroll
            for (int e = 0; e < 8; e++) {
                ra[e] = *reinterpret_cast<const float4*>(Fj + (size_t)(j0 + e) * 8);
                rb[e] = *reinterpret_cast<const float4*>(Fj + (size_t)(j0 + e) * 8 + 4);
            }
            bf16x8 bq = *reinterpret_cast<const bf16x8*>(&sQ[cur][n][ki * 16 + kb * 8]);
            bf16x8 ka;
            #pragma unroll
            for (int e = 0; e < 8; e++) {
                float bb = -(fB.y + rb[e].y);
                bb = fmaf(ra[e].x, fA.x, bb);
                bb = fmaf(ra[e].y, fA.y, bb);
                bb = fmaf(ra[e].z, fA.z, bb);
                bb = fmaf(ra[e].w, fA.w, bb);
                bb = fmaf(rb[e].x, fB.x, bb);
                ka[e] = (__bf16)fexp2(bb);
            }
            acc = __builtin_amdgcn_mfma_f32_32x32x16_bf16(ka, bq, acc, 0, 0, 0);
        }
        cur ^= 1;
    }
    if (n < 22) {
        float* p = part + ((size_t)jc * 22 + n) * NPIX + ibase;
        #pragma unroll
        for (int q = 0; q < 16; q++) {
            int r = (q & 3) + 8 * (q >> 2) + 4 * kb;   // verified C/D row map
            p[r] = acc[q];
        }
    }
}

// ---------- reduce j-chunks (22 rows incl. denominator) ----------
__global__ __launch_bounds__(256) void bredK(const float* __restrict__ part, float* __restrict__ Bl, int js) {
    int t = blockIdx.x * 256 + threadIdx.x;   // 22*NPIX = 202752 exact (792 blocks)
    float a = 0.f;
    for (int jc = 0; jc < js; jc++) a += part[(size_t)jc * 22 * NPIX + t];
    Bl[t] = a;
}

// ---------- combine (+ fused softmax for next iteration) ----------
__global__ __launch_bounds__(256) void combK(const float* __restrict__ Sp, const float* __restrict__ Bl,
                                             const float* __restrict__ Ms, const float* __restrict__ Mb,
                                             const float* __restrict__ unary, float* __restrict__ outp,
                                             __bf16* __restrict__ QhT, float* __restrict__ Qlm, int wq) {
    __shared__ float sMs[NL * NL], sMb[NL * NL];
    int t = threadIdx.x;
    for (int k = t; k < NL * NL; k += 256) { sMs[k] = Ms[k]; sMb[k] = Mb[k]; }
    __syncthreads();
    int i = blockIdx.x * 256 + t;
    if (i >= NPIX) return;
    float inv = 1.0f / (Bl[(size_t)21 * NPIX + i] + 1e-8f);
    float sp[NL], bl[NL], v[NL];
    #pragma unroll
    for (int p = 0; p < NL; p++) { sp[p] = Sp[p * NPIX + i]; bl[p] = Bl[p * NPIX + i] * inv; }
    #pragma unroll
    for (int l = 0; l < NL; l++) {
        float a = unary[l * NPIX + i];
        #pragma unroll
        for (int p = 0; p < NL; p++) {
            a = fmaf(sMs[l * NL + p], sp[p], a);
            a = fmaf(sMb[l * NL + p], bl[p], a);
        }
        outp[l * NPIX + i] = a;
        v[l] = a;
    }
    if (wq) {
        float m = -1e30f;
        #pragma unroll
        for (int l = 0; l < NL; l++) m = fmaxf(m, v[l]);
        float s = 0.f;
        #pragma unroll
        for (int l = 0; l < NL; l++) { v[l] = fexp2((v[l] - m) * L2E); s += v[l]; }
        float qi = 1.0f / s;
        #pragma unroll
        for (int l = 0; l < NL; l++) {
            float q = v[l] * qi;
            Qlm[l * NPIX + i] = q;
            QhT[(size_t)l * NPIX + i] = (__bf16)q;
        }
    }
}

extern "C" void kernel_launch(void* const* d_in, const int* in_sizes, int n_in,
                              void* d_out, int out_size, void* d_ws, size_t ws_size,
                              hipStream_t stream) {
    const float* img   = (const float*)d_in[0];
    const float* logit = (const float*)d_in[1];
    const float* Wsm   = (const float*)d_in[2];
    const float* Wbm   = (const float*)d_in[3];
    const float* Cm    = (const float*)d_in[4];
    float* out = (float*)d_out;
    float* ws  = (float*)d_ws;

    // workspace layout (float offsets)
    float* Fi     = ws;                       // 73728
    float* Fj     = Fi + NPIX * 8;            // 73728
    float* Qlm    = Fj + NPIX * 8;            // 193536
    float* S1     = Qlm + NL * NPIX;          // 193536
    float* Sp     = S1 + NL * NPIX;           // 193536
    float* Bl     = Sp + NL * NPIX;           // 202752 (22 rows)
    float* norm_s = Bl + 22 * NPIX;           // 9216
    float* Ms     = norm_s + NPIX;            // 448
    float* Mb     = Ms + 448;                 // 448
    __bf16* QhT   = (__bf16*)(Mb + 448);      // 32*NPIX bf16 = 147456 floats
    float* part   = ws + 1088384;             // js*22*NPIX

    int js = 32;
    while (js > 1 && (1088384ull + (size_t)js * 22 * NPIX) * 4 > ws_size) js >>= 1;
    int njc = NPIX / js;

    featK<<<36, 256, 0, stream>>>(img, Fi, Fj, norm_s, QhT);
    matK<<<1, 448, 0, stream>>>(Cm, Wsm, Wbm, Ms, Mb);
    softmaxK<<<36, 256, 0, stream>>>(logit, QhT, Qlm);
    for (int it = 0; it < 5; ++it) {
        spatX<<<756, 256, 0, stream>>>(Qlm, S1);
        spatY<<<756, 256, 0, stream>>>(S1, norm_s, Sp);
        bilatM<<<dim3(NPIX / 64, js), 128, 0, stream>>>(QhT, Fi, Fj, part, njc);
        bredK<<<792, 256, 0, stream>>>(part, Bl, js);
        combK<<<36, 256, 0, stream>>>(Sp, Bl, Ms, Mb, logit, out, QhT, Qlm, it < 4 ? 1 : 0);
    }
}

// Round 5
// 522.221 us; speedup vs baseline: 1.4287x; 1.3330x over previous
//
#include <hip/hip_runtime.h>

#define NPIX 9216
#define NL   21
#define WW   96
#define RAD  16
#define JS   16
#define L2E  1.44269504088896340736f

typedef __bf16 bf16x8 __attribute__((ext_vector_type(8)));
typedef float  f32x16 __attribute__((ext_vector_type(16)));

__device__ __forceinline__ float fexp2(float x) { return __builtin_amdgcn_exp2f(x); }

// ---------- prep: bilateral features + truncated spatial norm + QhT const rows ----------
__global__ __launch_bounds__(256) void featK(const float* __restrict__ img,
                                             float* __restrict__ Fi, float* __restrict__ Fj,
                                             float* __restrict__ norm_s, __bf16* __restrict__ QhT) {
    int i = blockIdx.x * 256 + threadIdx.x;
    if (i >= NPIX) return;
    int y = i / WW, x = i - y * WW;
    float f0 = (float)x * (1.0f / 160.0f);
    float f1 = (float)y * (1.0f / 160.0f);
    float f2 = img[0 * NPIX + i] * (1.0f / 3.0f);
    float f3 = img[1 * NPIX + i] * (1.0f / 3.0f);
    float f4 = img[2 * NPIX + i] * (1.0f / 3.0f);
    float st = 0.5f * (f0*f0 + f1*f1 + f2*f2 + f3*f3 + f4*f4) * L2E;
    float* a = Fi + (size_t)i * 8;
    float* b = Fj + (size_t)i * 8;
    a[0]=f0; a[1]=f1; a[2]=f2; a[3]=f3; a[4]=f4; a[5]=st; a[6]=0.f; a[7]=0.f;
    b[0]=f0*L2E; b[1]=f1*L2E; b[2]=f2*L2E; b[3]=f3*L2E; b[4]=f4*L2E; b[5]=st; b[6]=0.f; b[7]=0.f;
    QhT[(size_t)21 * NPIX + i] = (__bf16)1.0f;
    #pragma unroll
    for (int l = 22; l < 32; l++) QhT[(size_t)l * NPIX + i] = (__bf16)0.0f;
    const float cs = (-0.5f / 9.0f) * L2E;
    float sx = 0.f, sy = 0.f;
    int xa = max(0, x - RAD), xb = min(WW - 1, x + RAD);
    int ya = max(0, y - RAD), yb = min(WW - 1, y + RAD);
    for (int t = xa; t <= xb; t++) { float dx = (float)(x - t); sx += fexp2(cs * dx * dx); }
    for (int t = ya; t <= yb; t++) { float dy = (float)(y - t); sy += fexp2(cs * dy * dy); }
    norm_s[i] = 1.0f / (sx * sy + 1e-8f);
}

// ---------- fold 21x21 matrices ----------
__global__ __launch_bounds__(448) void matK(const float* __restrict__ Cm, const float* __restrict__ Wsm,
                                            const float* __restrict__ Wbm,
                                            float* __restrict__ Ms, float* __restrict__ Mb) {
    int t = threadIdx.x;
    if (t >= NL * NL) return;
    int l = t / NL, p = t - l * NL;
    float a = 0.f, b = 0.f;
    for (int m = 0; m < NL; m++) {
        float c = Cm[l * NL + m];
        a = fmaf(c, Wsm[m * NL + p], a);
        b = fmaf(c, Wbm[m * NL + p], b);
    }
    Ms[t] = a; Mb[t] = b;
}

// ---------- softmax over labels (iter 0 only) ----------
__global__ __launch_bounds__(256) void softmaxK(const float* __restrict__ cur,
                                                __bf16* __restrict__ QhT, float* __restrict__ Qlm) {
    int i = blockIdx.x * 256 + threadIdx.x;
    if (i >= NPIX) return;
    float v[NL]; float m = -1e30f;
    #pragma unroll
    for (int l = 0; l < NL; l++) { v[l] = cur[l * NPIX + i]; m = fmaxf(m, v[l]); }
    float s = 0.f;
    #pragma unroll
    for (int l = 0; l < NL; l++) { v[l] = fexp2((v[l] - m) * L2E); s += v[l]; }
    float inv = 1.0f / s;
    #pragma unroll
    for (int l = 0; l < NL; l++) {
        float q = v[l] * inv;
        Qlm[l * NPIX + i] = q;
        QhT[(size_t)l * NPIX + i] = (__bf16)q;
    }
}

// ---------- fused spatial filter: x-pass into LDS tile, y-pass out ----------
// block = (label l, 8-row band); halo rows (+-16) x-passed redundantly into LDS.
__global__ __launch_bounds__(256) void spatXY(const float* __restrict__ Qlm,
                                              const float* __restrict__ norm_s,
                                              float* __restrict__ Sp) {
    __shared__ float S1t[40][WW];
    __shared__ float wt[33];
    int l = blockIdx.x / 12, band = blockIdx.x - l * 12;
    int y0 = band * 8;
    int ya = max(0, y0 - RAD);
    int yb = min(WW - 1, y0 + 7 + RAD);
    int cnt = yb - ya + 1;                       // <= 40
    int t = threadIdx.x;
    const float cs = (-0.5f / 9.0f) * L2E;
    if (t < 33) { float d = (float)(t - RAD); wt[t] = fexp2(cs * d * d); }
    __syncthreads();
    const float* qbase = Qlm + l * NPIX;
    for (int idx = t; idx < cnt * WW; idx += 256) {
        int yy = idx / WW, x1 = idx - yy * WW;
        const float* row = qbase + (ya + yy) * WW;
        float acc = 0.f;
        #pragma unroll
        for (int d = 0; d < 33; d++) {
            int x2 = x1 - RAD + d;
            if ((unsigned)x2 < WW) acc = fmaf(wt[d], row[x2], acc);
        }
        S1t[yy][x1] = acc;
    }
    __syncthreads();
    for (int idx = t; idx < 8 * WW; idx += 256) {
        int y1 = y0 + idx / WW, x = idx - (idx / WW) * WW;
        float acc = 0.f;
        #pragma unroll
        for (int d = 0; d < 33; d++) {
            int y2 = y1 - RAD + d;
            if ((unsigned)y2 < WW) acc = fmaf(wt[d], S1t[y2 - ya][x], acc);
        }
        Sp[l * NPIX + y1 * WW + x] = acc * norm_s[y1 * WW + x];
    }
}

// ---------- bilateral via MFMA: fully LDS-resident inner loop ----------
// 128 threads (2 waves); wave owns 32 i-pixels; blockIdx.y = j-chunk (JS chunks).
// Per 64-j stage: Q tile [32][64] bf16 + Fj tile [64][8] f32, double-buffered,
// one barrier/stage, next-stage global loads issued before compute (T14).
__global__ __launch_bounds__(128, 4) void bilatM(const __bf16* __restrict__ QhT,
                                                 const float* __restrict__ Fi,
                                                 const float* __restrict__ Fj,
                                                 float* __restrict__ part, int njc) {
    __shared__ __bf16 sQ[2][32][72];   // 144B rows, 9216 B
    __shared__ float  sF[2][64][8];    // 4096 B
    int tid = threadIdx.x;
    int w = tid >> 6, lane = tid & 63;
    int n = lane & 31, kb = lane >> 5;
    int jc = blockIdx.y;
    int ibase = blockIdx.x * 64 + w * 32;
    int i = ibase + n;

    const float4 fA = *reinterpret_cast<const float4*>(Fi + (size_t)i * 8);
    const float4 fB = *reinterpret_cast<const float4*>(Fi + (size_t)i * 8 + 4);
    float nsum = -(fB.y);   // -si ; bb = -si - sj + dot

    // staging roles
    int qr = tid & 31, qc = tid >> 5;            // Q: row qr, chunks qc, qc+4 (8 bf16 each)
    int fr = tid >> 1, fh = tid & 1;             // F: row fr, half fh (float4)

    int jbeg = jc * njc;
    int nst = njc / 64;
    const __bf16* qsrc = QhT + (size_t)qr * NPIX + jbeg;
    const float*  fsrc = Fj + (size_t)jbeg * 8;

    // prologue: stage 0 into buffer 0
    float4 gq0 = *reinterpret_cast<const float4*>(qsrc + qc * 8);
    float4 gq1 = *reinterpret_cast<const float4*>(qsrc + (qc + 4) * 8);
    float4 gf  = *reinterpret_cast<const float4*>(fsrc + fr * 8 + fh * 4);
    *reinterpret_cast<float4*>(&sQ[0][qr][qc * 8])       = gq0;
    *reinterpret_cast<float4*>(&sQ[0][qr][(qc + 4) * 8]) = gq1;
    *reinterpret_cast<float4*>(&sF[0][fr][fh * 4])       = gf;

    f32x16 acc = {};
    int cur = 0;
    for (int s = 0; s < nst; s++) {
        __syncthreads();   // stage-s writes to buf[cur] visible; frees buf[cur^1]
        bool pf = (s + 1 < nst);
        if (pf) {
            int jo = (s + 1) * 64;
            gq0 = *reinterpret_cast<const float4*>(qsrc + jo + qc * 8);
            gq1 = *reinterpret_cast<const float4*>(qsrc + jo + (qc + 4) * 8);
            gf  = *reinterpret_cast<const float4*>(fsrc + (size_t)(jo + fr) * 8 + fh * 4);
        }
        #pragma unroll
        for (int kq = 0; kq < 4; kq++) {
            int jl = kq * 16 + kb * 8;
            bf16x8 bq = *reinterpret_cast<const bf16x8*>(&sQ[cur][n][jl]);
            bf16x8 ka;
            #pragma unroll
            for (int e = 0; e < 8; e++) {
                const float4 ra = *reinterpret_cast<const float4*>(&sF[cur][jl + e][0]);
                const float2 rb = *reinterpret_cast<const float2*>(&sF[cur][jl + e][4]);
                float bb = nsum - rb.y;
                bb = fmaf(ra.x, fA.x, bb);
                bb = fmaf(ra.y, fA.y, bb);
                bb = fmaf(ra.z, fA.z, bb);
                bb = fmaf(ra.w, fA.w, bb);
                bb = fmaf(rb.x, fB.x, bb);
                ka[e] = (__bf16)fexp2(bb);
            }
            acc = __builtin_amdgcn_mfma_f32_32x32x16_bf16(ka, bq, acc, 0, 0, 0);
        }
        if (pf) {
            int nx = cur ^ 1;
            *reinterpret_cast<float4*>(&sQ[nx][qr][qc * 8])       = gq0;
            *reinterpret_cast<float4*>(&sQ[nx][qr][(qc + 4) * 8]) = gq1;
            *reinterpret_cast<float4*>(&sF[nx][fr][fh * 4])       = gf;
        }
        cur ^= 1;
    }
    if (n < 22) {
        float* p = part + ((size_t)jc * 22 + n) * NPIX + ibase;
        #pragma unroll
        for (int q = 0; q < 16; q++) {
            int r = (q & 3) + 8 * (q >> 2) + 4 * kb;   // verified C/D row map
            p[r] = acc[q];
        }
    }
}

// ---------- reduce j-chunks (22 rows incl. denominator) ----------
__global__ __launch_bounds__(256) void bredK(const float* __restrict__ part, float* __restrict__ Bl, int js) {
    int t = blockIdx.x * 256 + threadIdx.x;   // 22*NPIX exact (792 blocks)
    float a = 0.f;
    for (int jc = 0; jc < js; jc++) a += part[(size_t)jc * 22 * NPIX + t];
    Bl[t] = a;
}

// ---------- combine (+ fused softmax for next iteration) ----------
__global__ __launch_bounds__(256) void combK(const float* __restrict__ Sp, const float* __restrict__ Bl,
                                             const float* __restrict__ Ms, const float* __restrict__ Mb,
                                             const float* __restrict__ unary, float* __restrict__ outp,
                                             __bf16* __restrict__ QhT, float* __restrict__ Qlm, int wq) {
    __shared__ float sMs[NL * NL], sMb[NL * NL];
    int t = threadIdx.x;
    for (int k = t; k < NL * NL; k += 256) { sMs[k] = Ms[k]; sMb[k] = Mb[k]; }
    __syncthreads();
    int i = blockIdx.x * 256 + t;
    if (i >= NPIX) return;
    float inv = 1.0f / (Bl[(size_t)21 * NPIX + i] + 1e-8f);
    float sp[NL], bl[NL], v[NL];
    #pragma unroll
    for (int p = 0; p < NL; p++) { sp[p] = Sp[p * NPIX + i]; bl[p] = Bl[p * NPIX + i] * inv; }
    #pragma unroll
    for (int l = 0; l < NL; l++) {
        float a = unary[l * NPIX + i];
        #pragma unroll
        for (int p = 0; p < NL; p++) {
            a = fmaf(sMs[l * NL + p], sp[p], a);
            a = fmaf(sMb[l * NL + p], bl[p], a);
        }
        outp[l * NPIX + i] = a;
        v[l] = a;
    }
    if (wq) {
        float m = -1e30f;
        #pragma unroll
        for (int l = 0; l < NL; l++) m = fmaxf(m, v[l]);
        float s = 0.f;
        #pragma unroll
        for (int l = 0; l < NL; l++) { v[l] = fexp2((v[l] - m) * L2E); s += v[l]; }
        float qi = 1.0f / s;
        #pragma unroll
        for (int l = 0; l < NL; l++) {
            float q = v[l] * qi;
            Qlm[l * NPIX + i] = q;
            QhT[(size_t)l * NPIX + i] = (__bf16)q;
        }
    }
}

extern "C" void kernel_launch(void* const* d_in, const int* in_sizes, int n_in,
                              void* d_out, int out_size, void* d_ws, size_t ws_size,
                              hipStream_t stream) {
    const float* img   = (const float*)d_in[0];
    const float* logit = (const float*)d_in[1];
    const float* Wsm   = (const float*)d_in[2];
    const float* Wbm   = (const float*)d_in[3];
    const float* Cm    = (const float*)d_in[4];
    float* out = (float*)d_out;
    float* ws  = (float*)d_ws;

    // workspace layout (float offsets)
    float* Fi     = ws;                       // 73728
    float* Fj     = Fi + NPIX * 8;            // 73728
    float* Qlm    = Fj + NPIX * 8;            // 193536
    float* Sp     = Qlm + NL * NPIX;          // 193536
    float* Bl     = Sp + NL * NPIX;           // 202752 (22 rows)
    float* norm_s = Bl + 22 * NPIX;           // 9216
    float* Ms     = norm_s + NPIX;            // 448
    float* Mb     = Ms + 448;                 // 448
    __bf16* QhT   = (__bf16*)(Mb + 448);      // 32*NPIX bf16 = 147456 floats
    float* part   = ws + 894848;              // js*22*NPIX

    int js = JS;
    while (js > 1 && (894848ull + (size_t)js * 22 * NPIX) * 4 > ws_size) js >>= 1;
    int njc = NPIX / js;

    featK<<<36, 256, 0, stream>>>(img, Fi, Fj, norm_s, QhT);
    matK<<<1, 448, 0, stream>>>(Cm, Wsm, Wbm, Ms, Mb);
    softmaxK<<<36, 256, 0, stream>>>(logit, QhT, Qlm);
    for (int it = 0; it < 5; ++it) {
        spatXY<<<NL * 12, 256, 0, stream>>>(Qlm, norm_s, Sp);
        bilatM<<<dim3(NPIX / 64, js), 128, 0, stream>>>(QhT, Fi, Fj, part, njc);
        bredK<<<792, 256, 0, stream>>>(part, Bl, js);
        combK<<<36, 256, 0, stream>>>(Sp, Bl, Ms, Mb, logit, out, QhT, Qlm, it < 4 ? 1 : 0);
    }
}

// Round 6
// 347.490 us; speedup vs baseline: 2.1472x; 1.5028x over previous
//
#include <hip/hip_runtime.h>

#define NPIX 9216
#define NL   21
#define WW   96
#define RAD  16
#define JS   16
#define L2E  1.44269504088896340736f

typedef __bf16 bf16x8 __attribute__((ext_vector_type(8)));
typedef float  f32x16 __attribute__((ext_vector_type(16)));

__device__ __forceinline__ float fexp2(float x) { return __builtin_amdgcn_exp2f(x); }

// ---------- prep: bilateral features + truncated spatial norm + QhT const rows ----------
__global__ __launch_bounds__(256) void featK(const float* __restrict__ img,
                                             float* __restrict__ Fi, float* __restrict__ Fj,
                                             float* __restrict__ norm_s, __bf16* __restrict__ QhT) {
    int i = blockIdx.x * 256 + threadIdx.x;
    if (i >= NPIX) return;
    int y = i / WW, x = i - y * WW;
    float f0 = (float)x * (1.0f / 160.0f);
    float f1 = (float)y * (1.0f / 160.0f);
    float f2 = img[0 * NPIX + i] * (1.0f / 3.0f);
    float f3 = img[1 * NPIX + i] * (1.0f / 3.0f);
    float f4 = img[2 * NPIX + i] * (1.0f / 3.0f);
    float st = 0.5f * (f0*f0 + f1*f1 + f2*f2 + f3*f3 + f4*f4) * L2E;
    float* a = Fi + (size_t)i * 8;
    float* b = Fj + (size_t)i * 8;
    a[0]=f0; a[1]=f1; a[2]=f2; a[3]=f3; a[4]=f4; a[5]=st; a[6]=0.f; a[7]=0.f;
    b[0]=f0*L2E; b[1]=f1*L2E; b[2]=f2*L2E; b[3]=f3*L2E; b[4]=f4*L2E; b[5]=st; b[6]=0.f; b[7]=0.f;
    QhT[(size_t)21 * NPIX + i] = (__bf16)1.0f;
    #pragma unroll
    for (int l = 22; l < 32; l++) QhT[(size_t)l * NPIX + i] = (__bf16)0.0f;
    const float cs = (-0.5f / 9.0f) * L2E;
    float sx = 0.f, sy = 0.f;
    int xa = max(0, x - RAD), xb = min(WW - 1, x + RAD);
    int ya = max(0, y - RAD), yb = min(WW - 1, y + RAD);
    for (int t = xa; t <= xb; t++) { float dx = (float)(x - t); sx += fexp2(cs * dx * dx); }
    for (int t = ya; t <= yb; t++) { float dy = (float)(y - t); sy += fexp2(cs * dy * dy); }
    norm_s[i] = 1.0f / (sx * sy + 1e-8f);
}

// ---------- fold 21x21 matrices ----------
__global__ __launch_bounds__(448) void matK(const float* __restrict__ Cm, const float* __restrict__ Wsm,
                                            const float* __restrict__ Wbm,
                                            float* __restrict__ Ms, float* __restrict__ Mb) {
    int t = threadIdx.x;
    if (t >= NL * NL) return;
    int l = t / NL, p = t - l * NL;
    float a = 0.f, b = 0.f;
    for (int m = 0; m < NL; m++) {
        float c = Cm[l * NL + m];
        a = fmaf(c, Wsm[m * NL + p], a);
        b = fmaf(c, Wbm[m * NL + p], b);
    }
    Ms[t] = a; Mb[t] = b;
}

// ---------- softmax over labels (iter 0 only) ----------
__global__ __launch_bounds__(256) void softmaxK(const float* __restrict__ cur,
                                                __bf16* __restrict__ QhT, float* __restrict__ Qlm) {
    int i = blockIdx.x * 256 + threadIdx.x;
    if (i >= NPIX) return;
    float v[NL]; float m = -1e30f;
    #pragma unroll
    for (int l = 0; l < NL; l++) { v[l] = cur[l * NPIX + i]; m = fmaxf(m, v[l]); }
    float s = 0.f;
    #pragma unroll
    for (int l = 0; l < NL; l++) { v[l] = fexp2((v[l] - m) * L2E); s += v[l]; }
    float inv = 1.0f / s;
    #pragma unroll
    for (int l = 0; l < NL; l++) {
        float q = v[l] * inv;
        Qlm[l * NPIX + i] = q;
        QhT[(size_t)l * NPIX + i] = (__bf16)q;
    }
}

// ---------- spatial filtering: truncated separable Gaussian, one output/thread ----------
__global__ __launch_bounds__(256) void spatX(const float* __restrict__ Qlm, float* __restrict__ S1) {
    __shared__ float wt[33];
    int t = threadIdx.x;
    if (t < 33) { float d = (float)(t - RAD); wt[t] = fexp2((-0.5f / 9.0f) * L2E * d * d); }
    __syncthreads();
    int tid = blockIdx.x * 256 + t;                 // NL*NPIX exact (756 blocks)
    int l = tid / NPIX, rem = tid - l * NPIX;
    int y = rem / WW, x1 = rem - y * WW;
    const float* row = Qlm + l * NPIX + y * WW;
    float acc = 0.f;
    #pragma unroll
    for (int d = 0; d < 33; d++) {
        int x2 = x1 - RAD + d;
        if ((unsigned)x2 < WW) acc = fmaf(wt[d], row[x2], acc);
    }
    S1[tid] = acc;
}

__global__ __launch_bounds__(256) void spatY(const float* __restrict__ S1, const float* __restrict__ norm_s,
                                             float* __restrict__ Sp) {
    __shared__ float wt[33];
    int t = threadIdx.x;
    if (t < 33) { float d = (float)(t - RAD); wt[t] = fexp2((-0.5f / 9.0f) * L2E * d * d); }
    __syncthreads();
    int tid = blockIdx.x * 256 + t;
    int l = tid / NPIX, rem = tid - l * NPIX;
    int y1 = rem / WW, x = rem - y1 * WW;
    const float* col = S1 + l * NPIX + x;
    float acc = 0.f;
    #pragma unroll
    for (int d = 0; d < 33; d++) {
        int y2 = y1 - RAD + d;
        if ((unsigned)y2 < WW) acc = fmaf(wt[d], col[y2 * WW], acc);
    }
    Sp[tid] = acc * norm_s[rem];
}

// ---------- bilateral via MFMA: fully LDS-resident inner loop ----------
__global__ __launch_bounds__(128, 4) void bilatM(const __bf16* __restrict__ QhT,
                                                 const float* __restrict__ Fi,
                                                 const float* __restrict__ Fj,
                                                 float* __restrict__ part, int njc) {
    __shared__ __bf16 sQ[2][32][72];   // 144B rows, 9216 B
    __shared__ float  sF[2][64][8];    // 4096 B
    int tid = threadIdx.x;
    int w = tid >> 6, lane = tid & 63;
    int n = lane & 31, kb = lane >> 5;
    int jc = blockIdx.y;
    int ibase = blockIdx.x * 64 + w * 32;
    int i = ibase + n;

    const float4 fA = *reinterpret_cast<const float4*>(Fi + (size_t)i * 8);
    const float4 fB = *reinterpret_cast<const float4*>(Fi + (size_t)i * 8 + 4);
    float nsum = -(fB.y);   // -si ; bb = -si - sj + dot

    int qr = tid & 31, qc = tid >> 5;            // Q: row qr, chunks qc, qc+4
    int fr = tid >> 1, fh = tid & 1;             // F: row fr, half fh (float4)

    int jbeg = jc * njc;
    int nst = njc / 64;
    const __bf16* qsrc = QhT + (size_t)qr * NPIX + jbeg;
    const float*  fsrc = Fj + (size_t)jbeg * 8;

    float4 gq0 = *reinterpret_cast<const float4*>(qsrc + qc * 8);
    float4 gq1 = *reinterpret_cast<const float4*>(qsrc + (qc + 4) * 8);
    float4 gf  = *reinterpret_cast<const float4*>(fsrc + fr * 8 + fh * 4);
    *reinterpret_cast<float4*>(&sQ[0][qr][qc * 8])       = gq0;
    *reinterpret_cast<float4*>(&sQ[0][qr][(qc + 4) * 8]) = gq1;
    *reinterpret_cast<float4*>(&sF[0][fr][fh * 4])       = gf;

    f32x16 acc = {};
    int cur = 0;
    for (int s = 0; s < nst; s++) {
        __syncthreads();
        bool pf = (s + 1 < nst);
        if (pf) {
            int jo = (s + 1) * 64;
            gq0 = *reinterpret_cast<const float4*>(qsrc + jo + qc * 8);
            gq1 = *reinterpret_cast<const float4*>(qsrc + jo + (qc + 4) * 8);
            gf  = *reinterpret_cast<const float4*>(fsrc + (size_t)(jo + fr) * 8 + fh * 4);
        }
        #pragma unroll
        for (int kq = 0; kq < 4; kq++) {
            int jl = kq * 16 + kb * 8;
            bf16x8 bq = *reinterpret_cast<const bf16x8*>(&sQ[cur][n][jl]);
            bf16x8 ka;
            #pragma unroll
            for (int e = 0; e < 8; e++) {
                const float4 ra = *reinterpret_cast<const float4*>(&sF[cur][jl + e][0]);
                const float2 rb = *reinterpret_cast<const float2*>(&sF[cur][jl + e][4]);
                float bb = nsum - rb.y;
                bb = fmaf(ra.x, fA.x, bb);
                bb = fmaf(ra.y, fA.y, bb);
                bb = fmaf(ra.z, fA.z, bb);
                bb = fmaf(ra.w, fA.w, bb);
                bb = fmaf(rb.x, fB.x, bb);
                ka[e] = (__bf16)fexp2(bb);
            }
            acc = __builtin_amdgcn_mfma_f32_32x32x16_bf16(ka, bq, acc, 0, 0, 0);
        }
        if (pf) {
            int nx = cur ^ 1;
            *reinterpret_cast<float4*>(&sQ[nx][qr][qc * 8])       = gq0;
            *reinterpret_cast<float4*>(&sQ[nx][qr][(qc + 4) * 8]) = gq1;
            *reinterpret_cast<float4*>(&sF[nx][fr][fh * 4])       = gf;
        }
        cur ^= 1;
    }
    if (n < 22) {
        float* p = part + ((size_t)jc * 22 + n) * NPIX + ibase;
        #pragma unroll
        for (int q = 0; q < 16; q++) {
            int r = (q & 3) + 8 * (q >> 2) + 4 * kb;   // verified C/D row map
            p[r] = acc[q];
        }
    }
}

// ---------- reduce j-chunks (22 rows incl. denominator) ----------
__global__ __launch_bounds__(256) void bredK(const float* __restrict__ part, float* __restrict__ Bl, int js) {
    int t = blockIdx.x * 256 + threadIdx.x;   // 22*NPIX exact (792 blocks)
    float a = 0.f;
    for (int jc = 0; jc < js; jc++) a += part[(size_t)jc * 22 * NPIX + t];
    Bl[t] = a;
}

// ---------- combine (+ fused softmax for next iteration) ----------
__global__ __launch_bounds__(256) void combK(const float* __restrict__ Sp, const float* __restrict__ Bl,
                                             const float* __restrict__ Ms, const float* __restrict__ Mb,
                                             const float* __restrict__ unary, float* __restrict__ outp,
                                             __bf16* __restrict__ QhT, float* __restrict__ Qlm, int wq) {
    __shared__ float sMs[NL * NL], sMb[NL * NL];
    int t = threadIdx.x;
    for (int k = t; k < NL * NL; k += 256) { sMs[k] = Ms[k]; sMb[k] = Mb[k]; }
    __syncthreads();
    int i = blockIdx.x * 256 + t;
    if (i >= NPIX) return;
    float inv = 1.0f / (Bl[(size_t)21 * NPIX + i] + 1e-8f);
    float sp[NL], bl[NL], v[NL];
    #pragma unroll
    for (int p = 0; p < NL; p++) { sp[p] = Sp[p * NPIX + i]; bl[p] = Bl[p * NPIX + i] * inv; }
    #pragma unroll
    for (int l = 0; l < NL; l++) {
        float a = unary[l * NPIX + i];
        #pragma unroll
        for (int p = 0; p < NL; p++) {
            a = fmaf(sMs[l * NL + p], sp[p], a);
            a = fmaf(sMb[l * NL + p], bl[p], a);
        }
        outp[l * NPIX + i] = a;
        v[l] = a;
    }
    if (wq) {
        float m = -1e30f;
        #pragma unroll
        for (int l = 0; l < NL; l++) m = fmaxf(m, v[l]);
        float s = 0.f;
        #pragma unroll
        for (int l = 0; l < NL; l++) { v[l] = fexp2((v[l] - m) * L2E); s += v[l]; }
        float qi = 1.0f / s;
        #pragma unroll
        for (int l = 0; l < NL; l++) {
            float q = v[l] * qi;
            Qlm[l * NPIX + i] = q;
            QhT[(size_t)l * NPIX + i] = (__bf16)q;
        }
    }
}

extern "C" void kernel_launch(void* const* d_in, const int* in_sizes, int n_in,
                              void* d_out, int out_size, void* d_ws, size_t ws_size,
                              hipStream_t stream) {
    const float* img   = (const float*)d_in[0];
    const float* logit = (const float*)d_in[1];
    const float* Wsm   = (const float*)d_in[2];
    const float* Wbm   = (const float*)d_in[3];
    const float* Cm    = (const float*)d_in[4];
    float* out = (float*)d_out;
    float* ws  = (float*)d_ws;

    // workspace layout (float offsets)
    float* Fi     = ws;                       // 73728
    float* Fj     = Fi + NPIX * 8;            // 73728
    float* Qlm    = Fj + NPIX * 8;            // 193536
    float* S1     = Qlm + NL * NPIX;          // 193536
    float* Sp     = S1 + NL * NPIX;           // 193536
    float* Bl     = Sp + NL * NPIX;           // 202752 (22 rows)
    float* norm_s = Bl + 22 * NPIX;           // 9216
    float* Ms     = norm_s + NPIX;            // 448
    float* Mb     = Ms + 448;                 // 448
    __bf16* QhT   = (__bf16*)(Mb + 448);      // 32*NPIX bf16 = 147456 floats
    float* part   = ws + 1088384;             // js*22*NPIX

    int js = JS;
    while (js > 1 && (1088384ull + (size_t)js * 22 * NPIX) * 4 > ws_size) js >>= 1;
    int njc = NPIX / js;

    featK<<<36, 256, 0, stream>>>(img, Fi, Fj, norm_s, QhT);
    matK<<<1, 448, 0, stream>>>(Cm, Wsm, Wbm, Ms, Mb);
    softmaxK<<<36, 256, 0, stream>>>(logit, QhT, Qlm);
    for (int it = 0; it < 5; ++it) {
        spatX<<<756, 256, 0, stream>>>(Qlm, S1);
        spatY<<<756, 256, 0, stream>>>(S1, norm_s, Sp);
        bilatM<<<dim3(NPIX / 64, js), 128, 0, stream>>>(QhT, Fi, Fj, part, njc);
        bredK<<<792, 256, 0, stream>>>(part, Bl, js);
        combK<<<36, 256, 0, stream>>>(Sp, Bl, Ms, Mb, logit, out, QhT, Qlm, it < 4 ? 1 : 0);
    }
}

// Round 7
// 279.706 us; speedup vs baseline: 2.6675x; 1.2423x over previous
//
#include <hip/hip_runtime.h>

#define NPIX 9216
#define NL   21
#define WW   96
#define RAD  16
#define JS   16
#define L2E  1.44269504088896340736f

typedef __bf16 bf16x8 __attribute__((ext_vector_type(8)));
typedef float  f32x16 __attribute__((ext_vector_type(16)));

__device__ __forceinline__ float fexp2(float x) { return __builtin_amdgcn_exp2f(x); }
__device__ __forceinline__ unsigned pkbf(float lo, float hi) {
    unsigned r;
    asm("v_cvt_pk_bf16_f32 %0, %1, %2" : "=v"(r) : "v"(lo), "v"(hi));
    return r;
}

// ---------- prep: bf16 feature fragments + truncated spatial norm + QhT const rows ----------
// Fj8[j][16] = [fj*L2E x5, sj', 1, 0...]   (A-side of dot MFMA)
// FiT8[i][16] = [fi x5, -1, -si', 0...]    (B-side)  =>  D = L2E*fi.fj - sj' - si'
__global__ __launch_bounds__(256) void featK(const float* __restrict__ img,
                                             __bf16* __restrict__ FiT8, __bf16* __restrict__ Fj8,
                                             float* __restrict__ norm_s, __bf16* __restrict__ QhT) {
    int i = blockIdx.x * 256 + threadIdx.x;
    if (i >= NPIX) return;
    int y = i / WW, x = i - y * WW;
    float f0 = (float)x * (1.0f / 160.0f);
    float f1 = (float)y * (1.0f / 160.0f);
    float f2 = img[0 * NPIX + i] * (1.0f / 3.0f);
    float f3 = img[1 * NPIX + i] * (1.0f / 3.0f);
    float f4 = img[2 * NPIX + i] * (1.0f / 3.0f);
    float st = 0.5f * (f0*f0 + f1*f1 + f2*f2 + f3*f3 + f4*f4) * L2E;
    __bf16* a = Fj8 + (size_t)i * 16;
    __bf16* b = FiT8 + (size_t)i * 16;
    a[0]=(__bf16)(f0*L2E); a[1]=(__bf16)(f1*L2E); a[2]=(__bf16)(f2*L2E);
    a[3]=(__bf16)(f3*L2E); a[4]=(__bf16)(f4*L2E); a[5]=(__bf16)st; a[6]=(__bf16)1.0f;
    b[0]=(__bf16)f0; b[1]=(__bf16)f1; b[2]=(__bf16)f2; b[3]=(__bf16)f3; b[4]=(__bf16)f4;
    b[5]=(__bf16)-1.0f; b[6]=(__bf16)(-st);
    #pragma unroll
    for (int k = 7; k < 16; k++) { a[k] = (__bf16)0.0f; b[k] = (__bf16)0.0f; }
    QhT[(size_t)21 * NPIX + i] = (__bf16)1.0f;
    #pragma unroll
    for (int l = 22; l < 32; l++) QhT[(size_t)l * NPIX + i] = (__bf16)0.0f;
    const float cs = (-0.5f / 9.0f) * L2E;
    float sx = 0.f, sy = 0.f;
    int xa = max(0, x - RAD), xb = min(WW - 1, x + RAD);
    int ya = max(0, y - RAD), yb = min(WW - 1, y + RAD);
    for (int t = xa; t <= xb; t++) { float dx = (float)(x - t); sx += fexp2(cs * dx * dx); }
    for (int t = ya; t <= yb; t++) { float dy = (float)(y - t); sy += fexp2(cs * dy * dy); }
    norm_s[i] = 1.0f / (sx * sy + 1e-8f);
}

// ---------- fold 21x21 matrices ----------
__global__ __launch_bounds__(448) void matK(const float* __restrict__ Cm, const float* __restrict__ Wsm,
                                            const float* __restrict__ Wbm,
                                            float* __restrict__ Ms, float* __restrict__ Mb) {
    int t = threadIdx.x;
    if (t >= NL * NL) return;
    int l = t / NL, p = t - l * NL;
    float a = 0.f, b = 0.f;
    for (int m = 0; m < NL; m++) {
        float c = Cm[l * NL + m];
        a = fmaf(c, Wsm[m * NL + p], a);
        b = fmaf(c, Wbm[m * NL + p], b);
    }
    Ms[t] = a; Mb[t] = b;
}

// ---------- softmax over labels (iter 0 only) ----------
__global__ __launch_bounds__(256) void softmaxK(const float* __restrict__ cur,
                                                __bf16* __restrict__ QhT, float* __restrict__ Qlm) {
    int i = blockIdx.x * 256 + threadIdx.x;
    if (i >= NPIX) return;
    float v[NL]; float m = -1e30f;
    #pragma unroll
    for (int l = 0; l < NL; l++) { v[l] = cur[l * NPIX + i]; m = fmaxf(m, v[l]); }
    float s = 0.f;
    #pragma unroll
    for (int l = 0; l < NL; l++) { v[l] = fexp2((v[l] - m) * L2E); s += v[l]; }
    float inv = 1.0f / s;
    #pragma unroll
    for (int l = 0; l < NL; l++) {
        float q = v[l] * inv;
        Qlm[l * NPIX + i] = q;
        QhT[(size_t)l * NPIX + i] = (__bf16)q;
    }
}

// ---------- spatial filtering: truncated separable Gaussian, one output/thread ----------
__global__ __launch_bounds__(256) void spatX(const float* __restrict__ Qlm, float* __restrict__ S1) {
    __shared__ float wt[33];
    int t = threadIdx.x;
    if (t < 33) { float d = (float)(t - RAD); wt[t] = fexp2((-0.5f / 9.0f) * L2E * d * d); }
    __syncthreads();
    int tid = blockIdx.x * 256 + t;                 // NL*NPIX exact (756 blocks)
    int l = tid / NPIX, rem = tid - l * NPIX;
    int y = rem / WW, x1 = rem - y * WW;
    const float* row = Qlm + l * NPIX + y * WW;
    float acc = 0.f;
    #pragma unroll
    for (int d = 0; d < 33; d++) {
        int x2 = x1 - RAD + d;
        if ((unsigned)x2 < WW) acc = fmaf(wt[d], row[x2], acc);
    }
    S1[tid] = acc;
}

__global__ __launch_bounds__(256) void spatY(const float* __restrict__ S1, const float* __restrict__ norm_s,
                                             float* __restrict__ Sp) {
    __shared__ float wt[33];
    int t = threadIdx.x;
    if (t < 33) { float d = (float)(t - RAD); wt[t] = fexp2((-0.5f / 9.0f) * L2E * d * d); }
    __syncthreads();
    int tid = blockIdx.x * 256 + t;
    int l = tid / NPIX, rem = tid - l * NPIX;
    int y1 = rem / WW, x = rem - y1 * WW;
    const float* col = S1 + l * NPIX + x;
    float acc = 0.f;
    #pragma unroll
    for (int d = 0; d < 33; d++) {
        int y2 = y1 - RAD + d;
        if ((unsigned)y2 < WW) acc = fmaf(wt[d], col[y2 * WW], acc);
    }
    Sp[tid] = acc * norm_s[rem];
}

// ---------- bilateral, attention-style: dot-MFMA -> exp2 -> in-register PV MFMA ----------
// 128 thr (2 waves); wave owns 32 i (cols); per 32-j tile:
//   D[j][i] = mfma(Fj8-frag, FiT8-frag, 0)     (bias terms folded into features)
//   S = exp2(D); cvt_pk + permlane32_swap assembles S as PV B-fragment in regs
//   acc[l][i] += mfma(Q^T-frag(from sQ), S-frag, acc)
__global__ __launch_bounds__(128, 4) void bilatM(const __bf16* __restrict__ QhT,
                                                 const __bf16* __restrict__ FiT8,
                                                 const __bf16* __restrict__ Fj8,
                                                 float* __restrict__ part, int njc) {
    __shared__ __bf16 sQ[2][32][72];    // 144B rows (16B-aligned reads)
    __shared__ __bf16 sFj[2][64][24];   // 48B rows
    int tid = threadIdx.x;
    int lane = tid & 63;
    int n = lane & 31, kb = lane >> 5;
    int jc = blockIdx.y;
    int w = tid >> 6;
    int ibase = blockIdx.x * 64 + w * 32;

    // B1 fragment: Fi features for this lane's i, constant across the j loop
    bf16x8 b1 = *reinterpret_cast<const bf16x8*>(FiT8 + (size_t)(ibase + n) * 16 + kb * 8);

    // staging roles
    int qr = tid >> 2, qc = tid & 3;          // sQ: row qr, float4 chunks qc, qc+4
    int fr = tid >> 1, fh = tid & 1;          // sFj: row fr, half fh
    int jbeg = jc * njc;
    int nst = njc / 64;
    const __bf16* qsrc = QhT + (size_t)qr * NPIX + jbeg;
    const __bf16* fsrc = Fj8 + (size_t)jbeg * 16;

    float4 gq0 = *reinterpret_cast<const float4*>(qsrc + qc * 8);
    float4 gq1 = *reinterpret_cast<const float4*>(qsrc + (qc + 4) * 8);
    float4 gf  = *reinterpret_cast<const float4*>(fsrc + fr * 16 + fh * 8);
    *reinterpret_cast<float4*>(&sQ[0][qr][qc * 8])       = gq0;
    *reinterpret_cast<float4*>(&sQ[0][qr][(qc + 4) * 8]) = gq1;
    *reinterpret_cast<float4*>(&sFj[0][fr][fh * 8])      = gf;

    f32x16 acc = {};
    int cur = 0;
    for (int s = 0; s < nst; s++) {
        __syncthreads();
        bool pf = (s + 1 < nst);
        if (pf) {
            int jo = (s + 1) * 64;
            gq0 = *reinterpret_cast<const float4*>(qsrc + jo + qc * 8);
            gq1 = *reinterpret_cast<const float4*>(qsrc + jo + (qc + 4) * 8);
            gf  = *reinterpret_cast<const float4*>(fsrc + (size_t)(jo + fr) * 16 + fh * 8);
        }
        #pragma unroll
        for (int t = 0; t < 2; t++) {
            int t32 = t * 32;
            // dot MFMA: A = Fj rows (j = t32+n per lane), B = b1 (i cols)
            bf16x8 a1 = *reinterpret_cast<const bf16x8*>(&sFj[cur][t32 + n][kb * 8]);
            f32x16 z = {};
            f32x16 d = __builtin_amdgcn_mfma_f32_32x32x16_bf16(a1, b1, z, 0, 0, 0);
            float e[16];
            #pragma unroll
            for (int q = 0; q < 16; q++) e[q] = fexp2(d[q]);
            #pragma unroll
            for (int h = 0; h < 2; h++) {
                // own quads (rows 8h..) + partner quads via permlane32_swap (r1<->r2)
                unsigned w0 = pkbf(e[8*h+0], e[8*h+1]);
                unsigned w1 = pkbf(e[8*h+2], e[8*h+3]);
                unsigned w2 = pkbf(e[8*h+4], e[8*h+5]);
                unsigned w3 = pkbf(e[8*h+6], e[8*h+7]);
                asm volatile("v_permlane32_swap_b32 %0, %1" : "+v"(w0), "+v"(w2));
                asm volatile("v_permlane32_swap_b32 %0, %1" : "+v"(w1), "+v"(w3));
                union { int4 u4; bf16x8 h8; } bb;
                bb.u4 = make_int4(w0, w1, w2, w3);
                bf16x8 qa = *reinterpret_cast<const bf16x8*>(&sQ[cur][n][t32 + h * 16 + kb * 8]);
                acc = __builtin_amdgcn_mfma_f32_32x32x16_bf16(qa, bb.h8, acc, 0, 0, 0);
            }
        }
        if (pf) {
            int nx = cur ^ 1;
            *reinterpret_cast<float4*>(&sQ[nx][qr][qc * 8])       = gq0;
            *reinterpret_cast<float4*>(&sQ[nx][qr][(qc + 4) * 8]) = gq1;
            *reinterpret_cast<float4*>(&sFj[nx][fr][fh * 8])      = gf;
        }
        cur ^= 1;
    }
    // acc: rows = labels l, cols = i (= lane n)
    float* p = part + (size_t)jc * 22 * NPIX + ibase + n;
    #pragma unroll
    for (int q = 0; q < 16; q++) {
        int l = (q & 3) + 8 * (q >> 2) + 4 * kb;   // verified C/D row map
        if (l < 22) p[(size_t)l * NPIX] = acc[q];
    }
}

// ---------- reduce j-chunks (22 rows incl. denominator) ----------
__global__ __launch_bounds__(256) void bredK(const float* __restrict__ part, float* __restrict__ Bl, int js) {
    int t = blockIdx.x * 256 + threadIdx.x;   // 22*NPIX exact (792 blocks)
    float a = 0.f;
    for (int jc = 0; jc < js; jc++) a += part[(size_t)jc * 22 * NPIX + t];
    Bl[t] = a;
}

// ---------- combine (+ fused softmax for next iteration) ----------
__global__ __launch_bounds__(256) void combK(const float* __restrict__ Sp, const float* __restrict__ Bl,
                                             const float* __restrict__ Ms, const float* __restrict__ Mb,
                                             const float* __restrict__ unary, float* __restrict__ outp,
                                             __bf16* __restrict__ QhT, float* __restrict__ Qlm, int wq) {
    __shared__ float sMs[NL * NL], sMb[NL * NL];
    int t = threadIdx.x;
    for (int k = t; k < NL * NL; k += 256) { sMs[k] = Ms[k]; sMb[k] = Mb[k]; }
    __syncthreads();
    int i = blockIdx.x * 256 + t;
    if (i >= NPIX) return;
    float inv = 1.0f / (Bl[(size_t)21 * NPIX + i] + 1e-8f);
    float sp[NL], bl[NL], v[NL];
    #pragma unroll
    for (int p = 0; p < NL; p++) { sp[p] = Sp[p * NPIX + i]; bl[p] = Bl[p * NPIX + i] * inv; }
    #pragma unroll
    for (int l = 0; l < NL; l++) {
        float a = unary[l * NPIX + i];
        #pragma unroll
        for (int p = 0; p < NL; p++) {
            a = fmaf(sMs[l * NL + p], sp[p], a);
            a = fmaf(sMb[l * NL + p], bl[p], a);
        }
        outp[l * NPIX + i] = a;
        v[l] = a;
    }
    if (wq) {
        float m = -1e30f;
        #pragma unroll
        for (int l = 0; l < NL; l++) m = fmaxf(m, v[l]);
        float s = 0.f;
        #pragma unroll
        for (int l = 0; l < NL; l++) { v[l] = fexp2((v[l] - m) * L2E); s += v[l]; }
        float qi = 1.0f / s;
        #pragma unroll
        for (int l = 0; l < NL; l++) {
            float q = v[l] * qi;
            Qlm[l * NPIX + i] = q;
            QhT[(size_t)l * NPIX + i] = (__bf16)q;
        }
    }
}

extern "C" void kernel_launch(void* const* d_in, const int* in_sizes, int n_in,
                              void* d_out, int out_size, void* d_ws, size_t ws_size,
                              hipStream_t stream) {
    const float* img   = (const float*)d_in[0];
    const float* logit = (const float*)d_in[1];
    const float* Wsm   = (const float*)d_in[2];
    const float* Wbm   = (const float*)d_in[3];
    const float* Cm    = (const float*)d_in[4];
    float* out = (float*)d_out;
    float* ws  = (float*)d_ws;

    // workspace layout (float offsets)
    __bf16* FiT8  = (__bf16*)ws;              // 9216*16 bf16 = 73728 floats
    __bf16* Fj8   = (__bf16*)(ws + 73728);    // 73728 floats
    float* Qlm    = ws + 147456;              // 193536
    float* S1     = Qlm + NL * NPIX;          // 193536
    float* Sp     = S1 + NL * NPIX;           // 193536
    float* Bl     = Sp + NL * NPIX;           // 202752 (22 rows)
    float* norm_s = Bl + 22 * NPIX;           // 9216
    float* Ms     = norm_s + NPIX;            // 448
    float* Mb     = Ms + 448;                 // 448
    __bf16* QhT   = (__bf16*)(Mb + 448);      // 32*NPIX bf16 = 147456 floats
    float* part   = ws + 1088384;             // js*22*NPIX

    int js = JS;
    while (js > 1 && (1088384ull + (size_t)js * 22 * NPIX) * 4 > ws_size) js >>= 1;
    int njc = NPIX / js;

    featK<<<36, 256, 0, stream>>>(img, FiT8, Fj8, norm_s, QhT);
    matK<<<1, 448, 0, stream>>>(Cm, Wsm, Wbm, Ms, Mb);
    softmaxK<<<36, 256, 0, stream>>>(logit, QhT, Qlm);
    for (int it = 0; it < 5; ++it) {
        spatX<<<756, 256, 0, stream>>>(Qlm, S1);
        spatY<<<756, 256, 0, stream>>>(S1, norm_s, Sp);
        bilatM<<<dim3(NPIX / 64, js), 128, 0, stream>>>(QhT, FiT8, Fj8, part, njc);
        bredK<<<792, 256, 0, stream>>>(part, Bl, js);
        combK<<<36, 256, 0, stream>>>(Sp, Bl, Ms, Mb, logit, out, QhT, Qlm, it < 4 ? 1 : 0);
    }
}